// Round 1
// baseline (390.910 us; speedup 1.0000x reference)
//
#include <hip/hip_runtime.h>

// Problem constants (fixed by the reference file)
constexpr int C = 32;
constexpr int H = 128;
constexpr int W = 512;
constexpr int PAD = 40;
constexpr int D = PAD + 1;   // 41 disparity planes
constexpr int W4 = W / 4;    // 128 float4 per row

// out[c][d][h][w] = (w >= d) ? in1[c][h][w] * in2[c][h][w-d] : 0
// Grid: x covers H*W4 float4-elements (64 blocks * 256 threads),
//       y = d (41), z = c (32). Stores are fully coalesced float4.
__global__ __launch_bounds__(256)
void corr1d_kernel(const float* __restrict__ in1,
                   const float* __restrict__ in2,
                   float* __restrict__ out) {
    const int tid = blockIdx.x * blockDim.x + threadIdx.x;  // [0, H*W4)
    const int d = blockIdx.y;
    const int c = blockIdx.z;

    const int h  = tid >> 7;        // / W4  (W4 == 128)
    const int w4 = tid & (W4 - 1);  // % W4
    const int w  = w4 * 4;

    const float* row1 = in1 + (c * H + h) * W;
    const float* row2 = in2 + (c * H + h) * W;

    const float4 a = *(const float4*)(row1 + w);

    // in2 index w+k-d, zero when negative
    const int base = w - d;
    float b0 = (base     >= 0) ? row2[base    ] : 0.0f;
    float b1 = (base + 1 >= 0) ? row2[base + 1] : 0.0f;
    float b2 = (base + 2 >= 0) ? row2[base + 2] : 0.0f;
    float b3 = (base + 3 >= 0) ? row2[base + 3] : 0.0f;

    float4 r;
    r.x = a.x * b0;
    r.y = a.y * b1;
    r.z = a.z * b2;
    r.w = a.w * b3;

    float4* outv = (float4*)out;
    outv[((c * D + d) * H + h) * W4 + w4] = r;
}

extern "C" void kernel_launch(void* const* d_in, const int* in_sizes, int n_in,
                              void* d_out, int out_size, void* d_ws, size_t ws_size,
                              hipStream_t stream) {
    const float* in1 = (const float*)d_in[0];
    const float* in2 = (const float*)d_in[1];
    float* out = (float*)d_out;

    dim3 block(256);
    dim3 grid((H * W4) / 256, D, C);  // (64, 41, 32)
    corr1d_kernel<<<grid, block, 0, stream>>>(in1, in2, out);
}

// Round 2
// 346.761 us; speedup vs baseline: 1.1273x; 1.1273x over previous
//
#include <hip/hip_runtime.h>

// Problem constants (fixed by the reference file)
constexpr int C = 32;
constexpr int H = 128;
constexpr int W = 512;
constexpr int PAD = 40;
constexpr int D = PAD + 1;   // 41 disparity planes
constexpr int W4 = W / 4;    // 128 float4 per row

// out[c][d][h][w] = (w >= d) ? in1[c][h][w] * in2[c][h][w-d] : 0
//
// One workgroup per (c, h-pair): 256 threads = 2 rows x 128 float4 slots.
// in2 row staged in LDS once; in1 float4 held in a register; loop over all
// 41 d-planes emitting one coalesced float4 store each. Global reads: each
// input element read exactly once. Kernel is pure-store-bound.
__global__ __launch_bounds__(256)
void corr1d_kernel(const float* __restrict__ in1,
                   const float* __restrict__ in2,
                   float* __restrict__ out) {
    const int c  = blockIdx.y;            // [0,32)
    const int h0 = blockIdx.x * 2;        // [0,128) step 2
    const int t  = threadIdx.x;
    const int r  = t >> 7;                // row within pair: 0/1
    const int w4 = t & (W4 - 1);          // float4 slot in row
    const int h  = h0 + r;

    __shared__ float4 s2[2][W4];          // 4 KB: two in2 rows

    const float4* in1v = (const float4*)in1;
    const float4* in2v = (const float4*)in2;
    const int rowIdx = (c * H + h) * W4;

    const float4 a = in1v[rowIdx + w4];   // stays in registers for all 41 d
    s2[r][w4] = in2v[rowIdx + w4];
    __syncthreads();

    float4* outv = (float4*)out;
    // out (float4 units): ((c*D + d)*H + h)*W4 + w4
    const int obase = (c * D * H + h) * W4 + w4;

    const float4 zero4 = make_float4(0.f, 0.f, 0.f, 0.f);

    #pragma unroll
    for (int d = 0; d <= PAD; ++d) {
        const int q  = d >> 2;            // float4 shift
        const int rr = d & 3;             // intra-float4 shift
        const int i0 = w4 - q;

        // b[k] = in2[4*w4 + k - d]; element (k-rr) of cur if k>=rr,
        // else element (4+k-rr) of prev. Out-of-range float4s are zero.
        const float4 cur  = (i0     >= 0) ? s2[r][i0]     : zero4;
        const float4 prev = (i0 - 1 >= 0) ? s2[r][i0 - 1] : zero4;

        float b0, b1, b2, b3;
        switch (rr) {                     // rr is a compile-time constant after unroll
            case 0:  b0 = cur.x;  b1 = cur.y;  b2 = cur.z;  b3 = cur.w; break;
            case 1:  b0 = prev.w; b1 = cur.x;  b2 = cur.y;  b3 = cur.z; break;
            case 2:  b0 = prev.z; b1 = prev.w; b2 = cur.x;  b3 = cur.y; break;
            default: b0 = prev.y; b1 = prev.z; b2 = prev.w; b3 = cur.x; break;
        }

        float4 res;
        res.x = a.x * b0;
        res.y = a.y * b1;
        res.z = a.z * b2;
        res.w = a.w * b3;

        outv[obase + d * H * W4] = res;
    }
}

extern "C" void kernel_launch(void* const* d_in, const int* in_sizes, int n_in,
                              void* d_out, int out_size, void* d_ws, size_t ws_size,
                              hipStream_t stream) {
    const float* in1 = (const float*)d_in[0];
    const float* in2 = (const float*)d_in[1];
    float* out = (float*)d_out;

    dim3 block(256);
    dim3 grid(H / 2, C);   // (64, 32) = 2048 workgroups, 4 waves each
    corr1d_kernel<<<grid, block, 0, stream>>>(in1, in2, out);
}